// Round 1
// baseline (2104.845 us; speedup 1.0000x reference)
//
#include <hip/hip_runtime.h>
#include <math.h>

#define B_ 2
#define S_ 2048          // SQ == SKV
#define D_ 1024
#define H_ 16
#define HD_ 64
#define BH_ (B_*H_)      // 32
#define OUT0_ (B_*S_*D_) // 4194304 floats (out), then attn

// ---------------------------------------------------------------------------
// Generic 64x64-tile fp32 GEMM: Y = X[4096x1024] * W[1024x1024] + bias
// mode 0: Y[m*1024+n]                      (standard row-major)
// mode 1: Y[((b*H + h)*S + s)*HD + f]      (per-head scatter; h = blockIdx.x)
// ---------------------------------------------------------------------------
__global__ __launch_bounds__(256) void gemm_kernel(
    const float* __restrict__ X, const float* __restrict__ W,
    const float* __restrict__ bias, float* __restrict__ Y, int mode)
{
    __shared__ __align__(16) float Xst[16][64];  // transposed: Xst[k][m]
    __shared__ __align__(16) float Ws[16][64];   // Ws[k][n]
    const int t  = threadIdx.x;
    const int tx = t & 15, ty = t >> 4;
    const int m0 = blockIdx.y * 64;
    const int n0 = blockIdx.x * 64;

    float acc[4][4] = {};

    for (int k0 = 0; k0 < 1024; k0 += 16) {
        // X tile: 64 rows x 16 k  (1 float4 per thread)
        {
            const int row = t >> 2, kq = (t & 3) * 4;
            const float4 v = *(const float4*)&X[(size_t)(m0 + row) * 1024 + k0 + kq];
            Xst[kq + 0][row] = v.x; Xst[kq + 1][row] = v.y;
            Xst[kq + 2][row] = v.z; Xst[kq + 3][row] = v.w;
        }
        // W tile: 16 k-rows x 64 n (1 float4 per thread, direct)
        {
            const int kr = t >> 4, nq = (t & 15) * 4;
            *(float4*)&Ws[kr][nq] = *(const float4*)&W[(size_t)(k0 + kr) * 1024 + n0 + nq];
        }
        __syncthreads();
#pragma unroll
        for (int k = 0; k < 16; ++k) {
            const float4 a = *(const float4*)&Xst[k][ty * 4];
            const float4 b = *(const float4*)&Ws[k][tx * 4];
            acc[0][0] += a.x * b.x; acc[0][1] += a.x * b.y; acc[0][2] += a.x * b.z; acc[0][3] += a.x * b.w;
            acc[1][0] += a.y * b.x; acc[1][1] += a.y * b.y; acc[1][2] += a.y * b.z; acc[1][3] += a.y * b.w;
            acc[2][0] += a.z * b.x; acc[2][1] += a.z * b.y; acc[2][2] += a.z * b.z; acc[2][3] += a.z * b.w;
            acc[3][0] += a.w * b.x; acc[3][1] += a.w * b.y; acc[3][2] += a.w * b.z; acc[3][3] += a.w * b.w;
        }
        __syncthreads();
    }

    const float4 bv = *(const float4*)&bias[n0 + tx * 4];
#pragma unroll
    for (int i = 0; i < 4; ++i) {
        const int m = m0 + ty * 4 + i;
        float4 v;
        v.x = acc[i][0] + bv.x; v.y = acc[i][1] + bv.y;
        v.z = acc[i][2] + bv.z; v.w = acc[i][3] + bv.w;
        if (mode == 0) {
            *(float4*)&Y[(size_t)m * 1024 + n0 + tx * 4] = v;
        } else {
            const int b = m >> 11, s = m & 2047;    // m = b*S + s
            const int h = blockIdx.x;               // n0 = h*64, tile width 64
            *(float4*)&Y[(((size_t)(b * H_ + h) * S_) + s) * HD_ + tx * 4] = v;
        }
    }
}

// ---------------------------------------------------------------------------
// Scores: attn[bh, q, k] = (Q[bh,q,:] . K[bh,k,:]) / 8   (raw, pre-softmax)
// ---------------------------------------------------------------------------
__global__ __launch_bounds__(256) void scores_kernel(
    const float* __restrict__ Qh, const float* __restrict__ Kh,
    float* __restrict__ attn)
{
    __shared__ __align__(16) float Qst[64][64];  // Qst[k][m]
    __shared__ __align__(16) float Kst[64][64];  // Kst[k][c]
    const int t  = threadIdx.x;
    const int bh = blockIdx.z;
    const int q0 = blockIdx.y * 64;
    const int c0 = blockIdx.x * 64;   // key tile

    const float* Qb = Qh + ((size_t)bh * S_ + q0) * HD_;
    const float* Kb = Kh + ((size_t)bh * S_ + c0) * HD_;

#pragma unroll
    for (int l = 0; l < 4; ++l) {
        const int fid = t + l * 256;
        const int row = fid >> 4, kq = (fid & 15) * 4;
        const float4 v = *(const float4*)&Qb[row * 64 + kq];
        Qst[kq + 0][row] = v.x; Qst[kq + 1][row] = v.y;
        Qst[kq + 2][row] = v.z; Qst[kq + 3][row] = v.w;
        const float4 w = *(const float4*)&Kb[row * 64 + kq];
        Kst[kq + 0][row] = w.x; Kst[kq + 1][row] = w.y;
        Kst[kq + 2][row] = w.z; Kst[kq + 3][row] = w.w;
    }
    __syncthreads();

    const int tx = t & 15, ty = t >> 4;
    float acc[4][4] = {};
#pragma unroll 16
    for (int k = 0; k < 64; ++k) {
        const float4 a = *(const float4*)&Qst[k][ty * 4];
        const float4 b = *(const float4*)&Kst[k][tx * 4];
        acc[0][0] += a.x * b.x; acc[0][1] += a.x * b.y; acc[0][2] += a.x * b.z; acc[0][3] += a.x * b.w;
        acc[1][0] += a.y * b.x; acc[1][1] += a.y * b.y; acc[1][2] += a.y * b.z; acc[1][3] += a.y * b.w;
        acc[2][0] += a.z * b.x; acc[2][1] += a.z * b.y; acc[2][2] += a.z * b.z; acc[2][3] += a.z * b.w;
        acc[3][0] += a.w * b.x; acc[3][1] += a.w * b.y; acc[3][2] += a.w * b.z; acc[3][3] += a.w * b.w;
    }

#pragma unroll
    for (int i = 0; i < 4; ++i) {
        float4 v;
        v.x = acc[i][0] * 0.125f; v.y = acc[i][1] * 0.125f;
        v.z = acc[i][2] * 0.125f; v.w = acc[i][3] * 0.125f;
        *(float4*)&attn[((size_t)bh * S_ + q0 + ty * 4 + i) * S_ + c0 + tx * 4] = v;
    }
}

// ---------------------------------------------------------------------------
// Row softmax over 2048 keys, in place. One block (256 thr) per row.
// ---------------------------------------------------------------------------
__global__ __launch_bounds__(256) void softmax_kernel(float* __restrict__ attn)
{
    float* p = attn + (size_t)blockIdx.x * S_;
    const int t = threadIdx.x;
    const int wid = t >> 6, lane = t & 63;
    __shared__ float redm[4];
    __shared__ float reds[4];

    float4 v0 = *(const float4*)&p[t * 4];
    float4 v1 = *(const float4*)&p[t * 4 + 1024];

    float m = fmaxf(fmaxf(fmaxf(v0.x, v0.y), fmaxf(v0.z, v0.w)),
                    fmaxf(fmaxf(v1.x, v1.y), fmaxf(v1.z, v1.w)));
#pragma unroll
    for (int off = 32; off > 0; off >>= 1) m = fmaxf(m, __shfl_xor(m, off));
    if (lane == 0) redm[wid] = m;
    __syncthreads();
    m = fmaxf(fmaxf(redm[0], redm[1]), fmaxf(redm[2], redm[3]));

    v0.x = __expf(v0.x - m); v0.y = __expf(v0.y - m);
    v0.z = __expf(v0.z - m); v0.w = __expf(v0.w - m);
    v1.x = __expf(v1.x - m); v1.y = __expf(v1.y - m);
    v1.z = __expf(v1.z - m); v1.w = __expf(v1.w - m);

    float s = v0.x + v0.y + v0.z + v0.w + v1.x + v1.y + v1.z + v1.w;
#pragma unroll
    for (int off = 32; off > 0; off >>= 1) s += __shfl_xor(s, off);
    if (lane == 0) reds[wid] = s;
    __syncthreads();
    const float inv = 1.0f / (reds[0] + reds[1] + reds[2] + reds[3]);

    v0.x *= inv; v0.y *= inv; v0.z *= inv; v0.w *= inv;
    v1.x *= inv; v1.y *= inv; v1.z *= inv; v1.w *= inv;
    *(float4*)&p[t * 4] = v0;
    *(float4*)&p[t * 4 + 1024] = v1;
}

// ---------------------------------------------------------------------------
// ctx[b, s, h*64+f] = sum_j attn[bh, s, j] * V[bh, j, f]
// ---------------------------------------------------------------------------
__global__ __launch_bounds__(256) void ctx_kernel(
    const float* __restrict__ attn, const float* __restrict__ Vh,
    float* __restrict__ ctx)
{
    __shared__ __align__(16) float Ast[64][64];  // Ast[j][q]
    __shared__ __align__(16) float Vs[64][64];   // Vs[j][f]
    const int t  = threadIdx.x;
    const int bh = blockIdx.y;
    const int q0 = blockIdx.x * 64;
    const int tx = t & 15, ty = t >> 4;
    const int b = bh >> 4, h = bh & 15;

    float acc[4][4] = {};

    for (int j0 = 0; j0 < S_; j0 += 64) {
#pragma unroll
        for (int l = 0; l < 4; ++l) {
            const int fid = t + l * 256;
            const int row = fid >> 4, jq = (fid & 15) * 4;
            const float4 v = *(const float4*)&attn[((size_t)bh * S_ + q0 + row) * S_ + j0 + jq];
            Ast[jq + 0][row] = v.x; Ast[jq + 1][row] = v.y;
            Ast[jq + 2][row] = v.z; Ast[jq + 3][row] = v.w;
            // here row = j index within tile, jq = f columns
            *(float4*)&Vs[row][jq] =
                *(const float4*)&Vh[((size_t)bh * S_ + j0 + row) * HD_ + jq];
        }
        __syncthreads();
#pragma unroll 16
        for (int j = 0; j < 64; ++j) {
            const float4 a = *(const float4*)&Ast[j][ty * 4];
            const float4 b4 = *(const float4*)&Vs[j][tx * 4];
            acc[0][0] += a.x * b4.x; acc[0][1] += a.x * b4.y; acc[0][2] += a.x * b4.z; acc[0][3] += a.x * b4.w;
            acc[1][0] += a.y * b4.x; acc[1][1] += a.y * b4.y; acc[1][2] += a.y * b4.z; acc[1][3] += a.y * b4.w;
            acc[2][0] += a.z * b4.x; acc[2][1] += a.z * b4.y; acc[2][2] += a.z * b4.z; acc[2][3] += a.z * b4.w;
            acc[3][0] += a.w * b4.x; acc[3][1] += a.w * b4.y; acc[3][2] += a.w * b4.z; acc[3][3] += a.w * b4.w;
        }
        __syncthreads();
    }

#pragma unroll
    for (int i = 0; i < 4; ++i) {
        const int s = q0 + ty * 4 + i;
        float4 v;
        v.x = acc[i][0]; v.y = acc[i][1]; v.z = acc[i][2]; v.w = acc[i][3];
        *(float4*)&ctx[((size_t)(b * S_ + s)) * 1024 + h * 64 + tx * 4] = v;
    }
}

extern "C" void kernel_launch(void* const* d_in, const int* in_sizes, int n_in,
                              void* d_out, int out_size, void* d_ws, size_t ws_size,
                              hipStream_t stream)
{
    const float* Xq  = (const float*)d_in[0];
    const float* Xkv = (const float*)d_in[1];
    const float* Wq  = (const float*)d_in[2];
    const float* bq  = (const float*)d_in[3];
    const float* Wk  = (const float*)d_in[4];
    const float* bk  = (const float*)d_in[5];
    const float* Wv  = (const float*)d_in[6];
    const float* bv  = (const float*)d_in[7];
    const float* Wo  = (const float*)d_in[8];
    const float* bo  = (const float*)d_in[9];

    float* out  = (float*)d_out;
    float* attn = out + OUT0_;

    float* ws  = (float*)d_ws;
    float* Qh  = ws;                       // [B,H,S,HD] 4M floats
    float* Kh  = ws + 1 * 4194304;
    float* Vh  = ws + 2 * 4194304;
    float* CTX = ws + 3 * 4194304;         // [B,S,H*HD]

    dim3 blk(256);

    // QKV projections -> per-head layout
    gemm_kernel<<<dim3(16, 64), blk, 0, stream>>>(Xq,  Wq, bq, Qh, 1);
    gemm_kernel<<<dim3(16, 64), blk, 0, stream>>>(Xkv, Wk, bk, Kh, 1);
    gemm_kernel<<<dim3(16, 64), blk, 0, stream>>>(Xkv, Wv, bv, Vh, 1);

    // raw scaled scores into attn output region
    scores_kernel<<<dim3(32, 32, 32), blk, 0, stream>>>(Qh, Kh, attn);

    // softmax in place (attn is output #1)
    softmax_kernel<<<dim3(BH_ * S_), blk, 0, stream>>>(attn);

    // context
    ctx_kernel<<<dim3(32, 32), blk, 0, stream>>>(attn, Vh, CTX);

    // output projection
    gemm_kernel<<<dim3(16, 64), blk, 0, stream>>>(CTX, Wo, bo, out, 0);

    (void)in_sizes; (void)n_in; (void)out_size; (void)ws_size;
}

// Round 2
// 1099.779 us; speedup vs baseline: 1.9139x; 1.9139x over previous
//
#include <hip/hip_runtime.h>
#include <math.h>

#define B_ 2
#define S_ 2048
#define D_ 1024
#define H_ 16
#define HD_ 64
#define BH_ (B_*H_)
#define OUT0_ (B_*S_*D_)

typedef __attribute__((ext_vector_type(8))) short bf16x8;   // 8 bf16 in 4 VGPRs
typedef __attribute__((ext_vector_type(4))) float floatx4;
typedef __attribute__((ext_vector_type(8))) short short8_t;
typedef __attribute__((ext_vector_type(4))) short short4_t;

static __device__ __forceinline__ short f2bf(float x) {
    union { float f; unsigned u; } c; c.f = x;
    unsigned r = (c.u + 0x7fffu + ((c.u >> 16) & 1u)) >> 16;
    return (short)r;
}

// ---------------------------------------------------------------------------
// fp32 -> bf16 convert, 4 elements/thread
// ---------------------------------------------------------------------------
__global__ __launch_bounds__(256) void cvt_kernel(
    const float* __restrict__ src, short* __restrict__ dst, int n4)
{
    int i = blockIdx.x * 256 + threadIdx.x;
    if (i >= n4) return;
    float4 v = *(const float4*)&src[(size_t)i * 4];
    short4_t o;
    o.x = f2bf(v.x); o.y = f2bf(v.y); o.z = f2bf(v.z); o.w = f2bf(v.w);
    *(short4_t*)&dst[(size_t)i * 4] = o;
}

// ---------------------------------------------------------------------------
// 1024x1024 fp32 -> bf16 transpose: dst[n][k] = src[k][n]
// ---------------------------------------------------------------------------
__global__ __launch_bounds__(256) void cvtT_kernel(
    const float* __restrict__ src, short* __restrict__ dst)
{
    __shared__ short Tl[64 * 72];
    const int t = threadIdx.x;
    const int r0 = blockIdx.y * 64;   // k rows
    const int c0 = blockIdx.x * 64;   // n cols
    {
        const int r = t >> 2, cq = t & 3;
#pragma unroll
        for (int u = 0; u < 4; ++u) {
            float4 v = *(const float4*)&src[(size_t)(r0 + r) * 1024 + c0 + cq * 16 + u * 4];
            Tl[r * 72 + cq * 16 + u * 4 + 0] = f2bf(v.x);
            Tl[r * 72 + cq * 16 + u * 4 + 1] = f2bf(v.y);
            Tl[r * 72 + cq * 16 + u * 4 + 2] = f2bf(v.z);
            Tl[r * 72 + cq * 16 + u * 4 + 3] = f2bf(v.w);
        }
    }
    __syncthreads();
    {
        const int c = t >> 2, rq = t & 3;
        short tmp[16];
#pragma unroll
        for (int u = 0; u < 16; ++u) tmp[u] = Tl[(rq * 16 + u) * 72 + c];
        *(short8_t*)&dst[(size_t)(c0 + c) * 1024 + r0 + rq * 16] = *(short8_t*)&tmp[0];
        *(short8_t*)&dst[(size_t)(c0 + c) * 1024 + r0 + rq * 16 + 8] = *(short8_t*)&tmp[8];
    }
}

// ---------------------------------------------------------------------------
// bf16 transpose per (b,h): Vt[bh][f][s] = Vh[bh][s][f]
// ---------------------------------------------------------------------------
__global__ __launch_bounds__(256) void transpose_v_kernel(
    const short* __restrict__ Vh, short* __restrict__ Vt)
{
    __shared__ short Tl[64 * 72];
    const int t = threadIdx.x;
    const int bh = blockIdx.y;
    const int s0 = blockIdx.x * 64;
    {
        const int r = t >> 2, cq = t & 3;  // r = s row, cq*16 = f chunk
        *(short8_t*)&Tl[r * 72 + cq * 16] =
            *(const short8_t*)&Vh[((size_t)bh * S_ + s0 + r) * HD_ + cq * 16];
        *(short8_t*)&Tl[r * 72 + cq * 16 + 8] =
            *(const short8_t*)&Vh[((size_t)bh * S_ + s0 + r) * HD_ + cq * 16 + 8];
    }
    __syncthreads();
    {
        const int f = t >> 2, rq = t & 3;
        short tmp[16];
#pragma unroll
        for (int u = 0; u < 16; ++u) tmp[u] = Tl[(rq * 16 + u) * 72 + f];
        *(short8_t*)&Vt[((size_t)bh * HD_ + f) * S_ + s0 + rq * 16] = *(short8_t*)&tmp[0];
        *(short8_t*)&Vt[((size_t)bh * HD_ + f) * S_ + s0 + rq * 16 + 8] = *(short8_t*)&tmp[8];
    }
}

// ---------------------------------------------------------------------------
// bf16 MFMA GEMM: Y = A[4096x1024] * Bt^T + bias.  Bt is [n][k] (pre-transposed).
// Tile 128x128, 4 waves (2x2), each wave 64x64 = 4x4 MFMA 16x16x32 frags.
// mode 0: fp32 out row-major [m][1024]
// mode 1: bf16 out scatter [((b*16+h)*2048+s)*64+f]  (b=m>>11,s=m&2047,h=n>>6,f=n&63)
// ---------------------------------------------------------------------------
__global__ __launch_bounds__(256) void gemm_bf16_kernel(
    const short* __restrict__ A, const short* __restrict__ Bt,
    const float* __restrict__ bias, void* __restrict__ Y, int mode)
{
    __shared__ short Al[128 * 40];
    __shared__ short Bl[128 * 40];
    const int t = threadIdx.x;
    const int w = t >> 6, lane = t & 63;
    const int quad = lane >> 4, l16 = lane & 15;
    const int wm = w >> 1, wn = w & 1;
    const int m0 = blockIdx.y * 128;
    const int n0 = blockIdx.x * 128;

    floatx4 acc[4][4] = {};

    const int r = t >> 1, h = t & 1;   // staging: row r, 16-short half h
    for (int k0 = 0; k0 < 1024; k0 += 32) {
        *(short8_t*)&Al[r * 40 + h * 16] =
            *(const short8_t*)&A[(size_t)(m0 + r) * 1024 + k0 + h * 16];
        *(short8_t*)&Al[r * 40 + h * 16 + 8] =
            *(const short8_t*)&A[(size_t)(m0 + r) * 1024 + k0 + h * 16 + 8];
        *(short8_t*)&Bl[r * 40 + h * 16] =
            *(const short8_t*)&Bt[(size_t)(n0 + r) * 1024 + k0 + h * 16];
        *(short8_t*)&Bl[r * 40 + h * 16 + 8] =
            *(const short8_t*)&Bt[(size_t)(n0 + r) * 1024 + k0 + h * 16 + 8];
        __syncthreads();
        bf16x8 a[4], b[4];
#pragma unroll
        for (int i = 0; i < 4; ++i)
            a[i] = *(const bf16x8*)&Al[(wm * 64 + i * 16 + l16) * 40 + quad * 8];
#pragma unroll
        for (int j = 0; j < 4; ++j)
            b[j] = *(const bf16x8*)&Bl[(wn * 64 + j * 16 + l16) * 40 + quad * 8];
#pragma unroll
        for (int i = 0; i < 4; ++i)
#pragma unroll
            for (int j = 0; j < 4; ++j)
                acc[i][j] = __builtin_amdgcn_mfma_f32_16x16x32_bf16(a[i], b[j], acc[i][j], 0, 0, 0);
        __syncthreads();
    }

#pragma unroll
    for (int i = 0; i < 4; ++i) {
#pragma unroll
        for (int j = 0; j < 4; ++j) {
            const int col = n0 + wn * 64 + j * 16 + l16;
            const float bcol = bias[col];
#pragma unroll
            for (int rr = 0; rr < 4; ++rr) {
                const int row = m0 + wm * 64 + i * 16 + quad * 4 + rr;
                const float v = acc[i][j][rr] + bcol;
                if (mode == 0) {
                    ((float*)Y)[(size_t)row * 1024 + col] = v;
                } else {
                    const int b = row >> 11, s = row & 2047;
                    const int hh = col >> 6, f = col & 63;
                    ((short*)Y)[(((size_t)(b * H_ + hh) * S_) + s) * HD_ + f] = f2bf(v);
                }
            }
        }
    }
}

// ---------------------------------------------------------------------------
// Scores MFMA: attn[bh][q][c] = (Q[bh][q][:] . K[bh][c][:]) / 8, fp32 out.
// Tile 128x128 over (q,c); K=64 (2 MFMA k-steps). grid (c/128, q/128, bh)
// ---------------------------------------------------------------------------
__global__ __launch_bounds__(256) void scores_mfma_kernel(
    const short* __restrict__ Qh, const short* __restrict__ Kh,
    float* __restrict__ attn)
{
    __shared__ short Ql[128 * 72];
    __shared__ short Kl[128 * 72];
    const int t = threadIdx.x;
    const int w = t >> 6, lane = t & 63;
    const int quad = lane >> 4, l16 = lane & 15;
    const int wm = w >> 1, wn = w & 1;
    const int bh = blockIdx.z;
    const int q0 = blockIdx.y * 128;
    const int c0 = blockIdx.x * 128;

    {   // stage: 128 rows x 64 shorts each; 2 threads/row, 32 shorts/thread
        const int r = t >> 1, h = t & 1;
        const short* qsrc = &Qh[((size_t)bh * S_ + q0 + r) * HD_ + h * 32];
        const short* ksrc = &Kh[((size_t)bh * S_ + c0 + r) * HD_ + h * 32];
#pragma unroll
        for (int u = 0; u < 4; ++u) {
            *(short8_t*)&Ql[r * 72 + h * 32 + u * 8] = *(const short8_t*)&qsrc[u * 8];
            *(short8_t*)&Kl[r * 72 + h * 32 + u * 8] = *(const short8_t*)&ksrc[u * 8];
        }
    }
    __syncthreads();

    floatx4 acc[4][4] = {};
#pragma unroll
    for (int ks = 0; ks < 2; ++ks) {
        bf16x8 a[4], b[4];
#pragma unroll
        for (int i = 0; i < 4; ++i)
            a[i] = *(const bf16x8*)&Ql[(wm * 64 + i * 16 + l16) * 72 + ks * 32 + quad * 8];
#pragma unroll
        for (int j = 0; j < 4; ++j)
            b[j] = *(const bf16x8*)&Kl[(wn * 64 + j * 16 + l16) * 72 + ks * 32 + quad * 8];
#pragma unroll
        for (int i = 0; i < 4; ++i)
#pragma unroll
            for (int j = 0; j < 4; ++j)
                acc[i][j] = __builtin_amdgcn_mfma_f32_16x16x32_bf16(a[i], b[j], acc[i][j], 0, 0, 0);
    }

#pragma unroll
    for (int i = 0; i < 4; ++i)
#pragma unroll
        for (int j = 0; j < 4; ++j) {
            const int col = c0 + wn * 64 + j * 16 + l16;
#pragma unroll
            for (int rr = 0; rr < 4; ++rr) {
                const int row = q0 + wm * 64 + i * 16 + quad * 4 + rr;
                attn[((size_t)bh * S_ + row) * S_ + col] = acc[i][j][rr] * 0.125f;
            }
        }
}

// ---------------------------------------------------------------------------
// Row softmax over 2048 keys, in place (fp32, exact). One block per row.
// ---------------------------------------------------------------------------
__global__ __launch_bounds__(256) void softmax_kernel(float* __restrict__ attn)
{
    float* p = attn + (size_t)blockIdx.x * S_;
    const int t = threadIdx.x;
    const int wid = t >> 6, lane = t & 63;
    __shared__ float redm[4];
    __shared__ float reds[4];

    float4 v0 = *(const float4*)&p[t * 4];
    float4 v1 = *(const float4*)&p[t * 4 + 1024];

    float m = fmaxf(fmaxf(fmaxf(v0.x, v0.y), fmaxf(v0.z, v0.w)),
                    fmaxf(fmaxf(v1.x, v1.y), fmaxf(v1.z, v1.w)));
#pragma unroll
    for (int off = 32; off > 0; off >>= 1) m = fmaxf(m, __shfl_xor(m, off));
    if (lane == 0) redm[wid] = m;
    __syncthreads();
    m = fmaxf(fmaxf(redm[0], redm[1]), fmaxf(redm[2], redm[3]));

    v0.x = __expf(v0.x - m); v0.y = __expf(v0.y - m);
    v0.z = __expf(v0.z - m); v0.w = __expf(v0.w - m);
    v1.x = __expf(v1.x - m); v1.y = __expf(v1.y - m);
    v1.z = __expf(v1.z - m); v1.w = __expf(v1.w - m);

    float s = v0.x + v0.y + v0.z + v0.w + v1.x + v1.y + v1.z + v1.w;
#pragma unroll
    for (int off = 32; off > 0; off >>= 1) s += __shfl_xor(s, off);
    if (lane == 0) reds[wid] = s;
    __syncthreads();
    const float inv = 1.0f / (reds[0] + reds[1] + reds[2] + reds[3]);

    v0.x *= inv; v0.y *= inv; v0.z *= inv; v0.w *= inv;
    v1.x *= inv; v1.y *= inv; v1.z *= inv; v1.w *= inv;
    *(float4*)&p[t * 4] = v0;
    *(float4*)&p[t * 4 + 1024] = v1;
}

// ---------------------------------------------------------------------------
// ctx MFMA: CTX[b*S+s][h*64+f] = sum_j attn[bh][s][j] * V[bh][j][f], bf16 out.
// Tile M=128 (4 waves x 32 rows), N=64, BK=32.  Vt is [bh][f][j].
// ---------------------------------------------------------------------------
__global__ __launch_bounds__(256) void ctx_mfma_kernel(
    const float* __restrict__ attn, const short* __restrict__ Vt,
    short* __restrict__ CTX)
{
    __shared__ short Aat[128 * 40];
    __shared__ short Vl[64 * 40];
    const int t = threadIdx.x;
    const int w = t >> 6, lane = t & 63;
    const int quad = lane >> 4, l16 = lane & 15;
    const int bh = blockIdx.y;
    const int q0 = blockIdx.x * 128;
    const int b = bh >> 4, hh = bh & 15;

    floatx4 acc[2][4] = {};

    for (int k0 = 0; k0 < S_; k0 += 32) {
        {   // A: 128 rows x 32 el from fp32 attn, convert
            const int r = t >> 1, h = t & 1;
            const float* src = &attn[((size_t)bh * S_ + q0 + r) * S_ + k0 + h * 16];
            short tmp[16];
#pragma unroll
            for (int u = 0; u < 4; ++u) {
                float4 v = *(const float4*)&src[u * 4];
                tmp[u * 4 + 0] = f2bf(v.x); tmp[u * 4 + 1] = f2bf(v.y);
                tmp[u * 4 + 2] = f2bf(v.z); tmp[u * 4 + 3] = f2bf(v.w);
            }
            *(short8_t*)&Aat[r * 40 + h * 16] = *(short8_t*)&tmp[0];
            *(short8_t*)&Aat[r * 40 + h * 16 + 8] = *(short8_t*)&tmp[8];
        }
        {   // V: 64 f-rows x 32 j from Vt (coalesced)
            const int f = t >> 2, q = t & 3;
            *(short8_t*)&Vl[f * 40 + q * 8] =
                *(const short8_t*)&Vt[((size_t)bh * HD_ + f) * S_ + k0 + q * 8];
        }
        __syncthreads();
        bf16x8 a[2], bfr[4];
#pragma unroll
        for (int i = 0; i < 2; ++i)
            a[i] = *(const bf16x8*)&Aat[(w * 32 + i * 16 + l16) * 40 + quad * 8];
#pragma unroll
        for (int j = 0; j < 4; ++j)
            bfr[j] = *(const bf16x8*)&Vl[(j * 16 + l16) * 40 + quad * 8];
#pragma unroll
        for (int i = 0; i < 2; ++i)
#pragma unroll
            for (int j = 0; j < 4; ++j)
                acc[i][j] = __builtin_amdgcn_mfma_f32_16x16x32_bf16(a[i], bfr[j], acc[i][j], 0, 0, 0);
        __syncthreads();
    }

#pragma unroll
    for (int i = 0; i < 2; ++i)
#pragma unroll
        for (int j = 0; j < 4; ++j) {
            const int col = j * 16 + l16;
#pragma unroll
            for (int rr = 0; rr < 4; ++rr) {
                const int s = q0 + w * 32 + i * 16 + quad * 4 + rr;
                CTX[((size_t)(b * S_ + s)) * 1024 + hh * 64 + col] = f2bf(acc[i][j][rr]);
            }
        }
}

extern "C" void kernel_launch(void* const* d_in, const int* in_sizes, int n_in,
                              void* d_out, int out_size, void* d_ws, size_t ws_size,
                              hipStream_t stream)
{
    const float* Xq  = (const float*)d_in[0];
    const float* Xkv = (const float*)d_in[1];
    const float* Wq  = (const float*)d_in[2];
    const float* bq  = (const float*)d_in[3];
    const float* Wk  = (const float*)d_in[4];
    const float* bk  = (const float*)d_in[5];
    const float* Wv  = (const float*)d_in[6];
    const float* bv  = (const float*)d_in[7];
    const float* Wo  = (const float*)d_in[8];
    const float* bo  = (const float*)d_in[9];

    float* out  = (float*)d_out;
    float* attn = out + OUT0_;

    short* ws = (short*)d_ws;
    short* XQB  = ws;                  // 4M shorts
    short* XKVB = ws + 4194304;
    short* WQT  = ws + 8388608;        // 1M each
    short* WKT  = ws + 9437184;
    short* WVT  = ws + 10485760;
    short* WOT  = ws + 11534336;
    short* QH   = ws + 12582912;       // [BH][S][HD] bf16, 4M each
    short* KH   = ws + 16777216;
    short* VH   = ws + 20971520;
    short* VT   = ws + 25165824;       // [BH][HD][S]
    short* CTXB = ws + 29360128;       // [B*S][1024]

    dim3 blk(256);

    cvt_kernel<<<dim3(4096), blk, 0, stream>>>(Xq,  XQB,  1048576);
    cvt_kernel<<<dim3(4096), blk, 0, stream>>>(Xkv, XKVB, 1048576);
    cvtT_kernel<<<dim3(16, 16), blk, 0, stream>>>(Wq, WQT);
    cvtT_kernel<<<dim3(16, 16), blk, 0, stream>>>(Wk, WKT);
    cvtT_kernel<<<dim3(16, 16), blk, 0, stream>>>(Wv, WVT);
    cvtT_kernel<<<dim3(16, 16), blk, 0, stream>>>(Wo, WOT);

    gemm_bf16_kernel<<<dim3(8, 32), blk, 0, stream>>>(XQB,  WQT, bq, QH, 1);
    gemm_bf16_kernel<<<dim3(8, 32), blk, 0, stream>>>(XKVB, WKT, bk, KH, 1);
    gemm_bf16_kernel<<<dim3(8, 32), blk, 0, stream>>>(XKVB, WVT, bv, VH, 1);

    transpose_v_kernel<<<dim3(32, 32), blk, 0, stream>>>(VH, VT);

    scores_mfma_kernel<<<dim3(16, 16, 32), blk, 0, stream>>>(QH, KH, attn);
    softmax_kernel<<<dim3(BH_ * S_), blk, 0, stream>>>(attn);
    ctx_mfma_kernel<<<dim3(16, 32), blk, 0, stream>>>(attn, VT, CTXB);

    gemm_bf16_kernel<<<dim3(8, 32), blk, 0, stream>>>(CTXB, WOT, bo, out, 0);

    (void)in_sizes; (void)n_in; (void)out_size; (void)ws_size;
}